// Round 7
// baseline (344.923 us; speedup 1.0000x reference)
//
#include <hip/hip_runtime.h>
#include <hip/hip_bf16.h>
#include <math.h>

#define N_TS   19000
#define M_PAD  19072      // 1192 * 16
#define ROWS   16         // rows per block
#define T_DIM  168
#define T_PAD  192        // 6 * 32
#define U_DIM  256
#define NBLK   3
#define HOR    24

using bf16 = __hip_bfloat16;
typedef short v8s __attribute__((ext_vector_type(8)));   // 8 bf16 (MFMA A/B frag)
typedef float v4f __attribute__((ext_vector_type(4)));   // MFMA C/D frag

// fast softplus: max(z,0) + log(1+exp(-|z|)) with native exp/log.
__device__ __forceinline__ float softplus_f(float z) {
    return fmaxf(z, 0.0f) + __logf(1.0f + __expf(-fabsf(z)));
}
__device__ __forceinline__ unsigned pack2bf(float a, float b) {
    __hip_bfloat162 t = __float22bfloat162_rn(make_float2(a, b));
    return *(unsigned*)&t;
}
__device__ __forceinline__ short f2bf_s(float x) {
    bf16 h = __float2bfloat16(x); return *(short*)&h;
}
__device__ __forceinline__ v8s make_v8(float4 f0, float4 f1) {
    v8s r;
    r[0] = f2bf_s(f0.x); r[1] = f2bf_s(f0.y); r[2] = f2bf_s(f0.z); r[3] = f2bf_s(f0.w);
    r[4] = f2bf_s(f1.x); r[5] = f2bf_s(f1.y); r[6] = f2bf_s(f1.z); r[7] = f2bf_s(f1.w);
    return r;
}

// ---------------------------------------------------------------------------
// Weight prep (layout unchanged from round 4):
//  [0,768):     Wvo[b] = Wo[b]@Wv[b] -> bf16; bvo = Wo@bv + bo (f32)
//  [768,1536):  Wl  -> bf16, K-pad 168->192
//  [1536,2304): Wl1 -> bf16
//  [2304,2880): W20 -> bf16, rows padded 168->192 (zeros)
//  [2880,2912): Wfc2 -> bf16, rows 24->32 (zeros), K-pad 168->192
// ---------------------------------------------------------------------------
__global__ __launch_bounds__(256) void wprep(
    const float* __restrict__ Wl, const float* __restrict__ Wl1,
    const float* __restrict__ Wv, const float* __restrict__ bv,
    const float* __restrict__ Wo, const float* __restrict__ bo,
    const float* __restrict__ W20, const float* __restrict__ Wfc2,
    bf16* __restrict__ Wlb, bf16* __restrict__ Wl1b, bf16* __restrict__ Wvob,
    bf16* __restrict__ W20b, bf16* __restrict__ Wfc2b, float* __restrict__ bvo)
{
    const int blk = blockIdx.x, j = threadIdx.x;
    if (blk < 768) {
        const int b = blk >> 8, n = blk & 255;
        const float* Wo_row = Wo + (size_t)(b * 256 + n) * 256;
        const float* Wv_b   = Wv + (size_t)b * 65536;
        float acc = 0.f;
        #pragma unroll 8
        for (int t = 0; t < 256; ++t)
            acc = fmaf(Wo_row[t], Wv_b[(size_t)t * 256 + j], acc);
        Wvob[(size_t)(b * 256 + n) * 256 + j] = __float2bfloat16(acc);
        __shared__ float red[256];
        red[j] = Wo_row[j] * bv[b * 256 + j];
        __syncthreads();
        for (int s = 128; s > 0; s >>= 1) { if (j < s) red[j] += red[j + s]; __syncthreads(); }
        if (j == 0) bvo[b * 256 + n] = red[0] + bo[b * 256 + n];
    } else if (blk < 1536) {
        const int idx = blk - 768, b = idx >> 8, r = idx & 255;
        if (j < T_PAD)
            Wlb[(size_t)(b * 256 + r) * T_PAD + j] =
                __float2bfloat16(j < T_DIM ? Wl[(size_t)(b * 256 + r) * T_DIM + j] : 0.f);
    } else if (blk < 2304) {
        const int idx = blk - 1536, b = idx >> 8, r = idx & 255;
        Wl1b[(size_t)(b * 256 + r) * 256 + j] =
            __float2bfloat16(Wl1[(size_t)(b * 256 + r) * 256 + j]);
    } else if (blk < 2880) {
        const int idx = blk - 2304, b = idx / T_PAD, r = idx % T_PAD;
        W20b[(size_t)(b * T_PAD + r) * 256 + j] =
            __float2bfloat16(r < T_DIM ? W20[(size_t)(b * T_DIM + r) * 256 + j] : 0.f);
    } else {
        const int r = blk - 2880;   // 0..31
        if (j < T_PAD)
            Wfc2b[r * T_PAD + j] =
                __float2bfloat16((r < HOR && j < T_DIM) ? Wfc2[r * T_DIM + j] : 0.f);
    }
}

// x (f32, 19000x168) -> Xf (f32, padded 19072x192) + xb (bf16 copy)
__global__ __launch_bounds__(256) void convert_x(
    const float* __restrict__ x, float* __restrict__ Xf, bf16* __restrict__ xb)
{
    const int i = blockIdx.x * 256 + threadIdx.x;
    const int r = i / T_PAD, c = i - r * T_PAD;
    const float v = (r < N_TS && c < T_DIM) ? x[(size_t)r * T_DIM + c] : 0.f;
    Xf[i] = v;
    xb[i] = __float2bfloat16(v);
}

// ---------------------------------------------------------------------------
// Fused network. ROWS=16 rows/block, 4 waves; wave w owns h-cols [64w,64w+64).
// Swapped MFMA: A = weight rows (global, L2-hot), B = activation rows.
// LDS h layout: elem (row,col) at byte row*512 + ((2*col) ^ ((row&7)<<4)).
// D frag: lane (r16,kq) holds h[row=r16][cols 64w+16i+4kq+r], r=0..3.
// ---------------------------------------------------------------------------
template<bool SP, bool BIAS>
__device__ __forceinline__ void gemm_h2h(const bf16* __restrict__ W,
                                         const float* __restrict__ bias,
                                         const bf16* src, bf16* dst,
                                         int w, int r16, int kq, int swz)
{
    v4f acc[4] = {};
    #pragma unroll 4
    for (int ks = 0; ks < 8; ++ks) {
        v8s bfr = *(const v8s*)((const char*)src + r16 * 512 +
                                ((ks * 64 + 16 * kq) ^ swz));
        #pragma unroll
        for (int i = 0; i < 4; ++i) {
            v8s a = *(const v8s*)&W[(size_t)(64 * w + 16 * i + r16) * 256 + ks * 32 + 8 * kq];
            acc[i] = __builtin_amdgcn_mfma_f32_16x16x32_bf16(a, bfr, acc[i], 0, 0, 0);
        }
    }
    #pragma unroll
    for (int i = 0; i < 4; ++i) {
        float v0 = acc[i][0], v1 = acc[i][1], v2 = acc[i][2], v3 = acc[i][3];
        const int c0 = 64 * w + 16 * i + 4 * kq;
        if (BIAS) {
            float4 bb = *(const float4*)&bias[c0];
            v0 += bb.x; v1 += bb.y; v2 += bb.z; v3 += bb.w;
        }
        if (SP) { v0 = softplus_f(v0); v1 = softplus_f(v1);
                  v2 = softplus_f(v2); v3 = softplus_f(v3); }
        const int off = r16 * 512 + ((2 * c0) ^ swz);
        *(uint2*)((char*)dst + off) = make_uint2(pack2bf(v0, v1), pack2bf(v2, v3));
    }
}

__global__ __launch_bounds__(256, 4) void fused_net(
    const bf16* __restrict__ Wlb, const bf16* __restrict__ Wl1b,
    const bf16* __restrict__ Wvob, const bf16* __restrict__ W20b,
    const bf16* __restrict__ Wfc2b, const float* __restrict__ bvo,
    float* __restrict__ Xf, bf16* __restrict__ xb, float* __restrict__ out)
{
    __shared__ __align__(16) bf16 hA[ROWS * 256];
    __shared__ __align__(16) bf16 hB[ROWS * 256];

    const int tid  = threadIdx.x;
    const int lane = tid & 63, w = tid >> 6;       // 4 waves
    const int r16  = lane & 15, kq = lane >> 4;
    const int swz  = (r16 & 7) << 4;
    const int bm   = blockIdx.x * ROWS;

    for (int b = 0; b < NBLK; ++b) {
        // ---- GEMM1: hA = softplus(xb @ Wl^T), K=192, B-frags direct bf16 ----
        {
            const bf16* W    = Wlb + (size_t)b * 256 * T_PAD;
            const bf16* xrow = xb + (size_t)(bm + r16) * T_PAD;
            v4f acc[4] = {};
            #pragma unroll 3
            for (int ks = 0; ks < 6; ++ks) {
                v8s bfr = *(const v8s*)&xrow[ks * 32 + 8 * kq];
                #pragma unroll
                for (int i = 0; i < 4; ++i) {
                    v8s a = *(const v8s*)&W[(size_t)(64 * w + 16 * i + r16) * T_PAD + ks * 32 + 8 * kq];
                    acc[i] = __builtin_amdgcn_mfma_f32_16x16x32_bf16(a, bfr, acc[i], 0, 0, 0);
                }
            }
            #pragma unroll
            for (int i = 0; i < 4; ++i) {
                float v0 = softplus_f(acc[i][0]), v1 = softplus_f(acc[i][1]);
                float v2 = softplus_f(acc[i][2]), v3 = softplus_f(acc[i][3]);
                const int c0  = 64 * w + 16 * i + 4 * kq;
                const int off = r16 * 512 + ((2 * c0) ^ swz);
                *(uint2*)((char*)hA + off) = make_uint2(pack2bf(v0, v1), pack2bf(v2, v3));
            }
        }
        __syncthreads();
        // ---- GEMM2: hB = softplus(hA @ Wl1^T) ----
        gemm_h2h<true, false>(Wl1b + (size_t)b * 65536, nullptr, hA, hB, w, r16, kq, swz);
        __syncthreads();
        // ---- GEMM3: hA = hB @ Wvo^T + bvo ----
        gemm_h2h<false, true>(Wvob + (size_t)b * 65536, bvo + b * 256, hB, hA, w, r16, kq, swz);
        __syncthreads();
        // ---- GEMM4: Xf += hA @ W20^T; wave w owns x-cols [48w,48w+48) ----
        {
            const bf16* W = W20b + (size_t)b * T_PAD * 256;
            v4f acc[3] = {};
            #pragma unroll 4
            for (int ks = 0; ks < 8; ++ks) {
                v8s bfr = *(const v8s*)((const char*)hA + r16 * 512 +
                                        ((ks * 64 + 16 * kq) ^ swz));
                #pragma unroll
                for (int i = 0; i < 3; ++i) {
                    v8s a = *(const v8s*)&W[(size_t)(48 * w + 16 * i + r16) * 256 + ks * 32 + 8 * kq];
                    acc[i] = __builtin_amdgcn_mfma_f32_16x16x32_bf16(a, bfr, acc[i], 0, 0, 0);
                }
            }
            const size_t row = (size_t)(bm + r16);
            #pragma unroll
            for (int i = 0; i < 3; ++i) {
                const int c0 = 48 * w + 16 * i + 4 * kq;
                float4* p = (float4*)&Xf[row * T_PAD + c0];
                float4 v = *p;
                v.x += acc[i][0]; v.y += acc[i][1];
                v.z += acc[i][2]; v.w += acc[i][3];
                *p = v;
                *(uint2*)&xb[row * T_PAD + c0] =
                    make_uint2(pack2bf(v.x, v.y), pack2bf(v.z, v.w));
            }
        }
        __syncthreads();
    }

    // ---- fc2: out = X @ Wfc2^T; waves 0,1 take out-col tiles 0,1 ----
    if (w < 2) {
        v4f acc = {};
        #pragma unroll 3
        for (int ks = 0; ks < 6; ++ks) {
            const float* xr = Xf + (size_t)(bm + r16) * T_PAD + ks * 32 + 8 * kq;
            float4 f0 = *(const float4*)xr;
            float4 f1 = *(const float4*)(xr + 4);
            v8s xv = make_v8(f0, f1);
            v8s a  = *(const v8s*)&Wfc2b[(size_t)(16 * w + r16) * T_PAD + ks * 32 + 8 * kq];
            acc = __builtin_amdgcn_mfma_f32_16x16x32_bf16(a, xv, acc, 0, 0, 0);
        }
        const int row = bm + r16;
        const int c0  = 16 * w + 4 * kq;
        if (row < N_TS && c0 < HOR) {
            *(float4*)&out[(size_t)row * HOR + c0] =
                make_float4(acc[0], acc[1], acc[2], acc[3]);
        }
    }
}

// ---------------------------------------------------------------------------
extern "C" void kernel_launch(void* const* d_in, const int* in_sizes, int n_in,
                              void* d_out, int out_size, void* d_ws, size_t ws_size,
                              hipStream_t stream) {
    const float* x    = (const float*)d_in[0];
    const float* Wl   = (const float*)d_in[1];
    const float* Wl1  = (const float*)d_in[2];
    const float* Wv   = (const float*)d_in[7];
    const float* bv   = (const float*)d_in[8];
    const float* Wo   = (const float*)d_in[9];
    const float* bo   = (const float*)d_in[10];
    const float* W20  = (const float*)d_in[11];
    const float* Wfc2 = (const float*)d_in[12];
    float* out = (float*)d_out;

    char* p = (char*)d_ws;
    auto carve = [&](size_t bytes) { char* q = p; p += (bytes + 255) & ~(size_t)255; return q; };
    bf16*  Wlb   = (bf16*)carve((size_t)NBLK * 256 * T_PAD * 2);
    bf16*  Wl1b  = (bf16*)carve((size_t)NBLK * 256 * 256 * 2);
    bf16*  Wvob  = (bf16*)carve((size_t)NBLK * 256 * 256 * 2);
    bf16*  W20b  = (bf16*)carve((size_t)NBLK * T_PAD * 256 * 2);
    bf16*  Wfc2b = (bf16*)carve((size_t)32 * T_PAD * 2);
    float* bvo   = (float*)carve((size_t)NBLK * 256 * 4);
    float* Xf    = (float*)carve((size_t)M_PAD * T_PAD * 4);
    bf16*  xb    = (bf16*)carve((size_t)M_PAD * T_PAD * 2);

    wprep<<<dim3(2912), dim3(256), 0, stream>>>(
        Wl, Wl1, Wv, bv, Wo, bo, W20, Wfc2, Wlb, Wl1b, Wvob, W20b, Wfc2b, bvo);
    convert_x<<<dim3((M_PAD * T_PAD) / 256), dim3(256), 0, stream>>>(x, Xf, xb);
    fused_net<<<dim3(M_PAD / ROWS), dim3(256), 0, stream>>>(
        Wlb, Wl1b, Wvob, W20b, Wfc2b, bvo, Xf, xb, out);
}

// Round 9
// 173.798 us; speedup vs baseline: 1.9846x; 1.9846x over previous
//
#include <hip/hip_runtime.h>
#include <hip/hip_bf16.h>
#include <math.h>

#define N_TS   19000
#define RPB    80         // rows per block (5 j-tiles of 16)
#define NBLKS  238        // 238*80 = 19040 >= 19000
#define T_DIM  168
#define T_PAD  192        // 6 * 32
#define U_DIM  256
#define NBLK   3
#define HOR    24

using bf16 = __hip_bfloat16;
typedef short v8s __attribute__((ext_vector_type(8)));   // 8 bf16 (MFMA A/B frag)
typedef float v4f __attribute__((ext_vector_type(4)));   // MFMA C/D frag

__device__ __forceinline__ float softplus_f(float z) {
    return fmaxf(z, 0.0f) + __logf(1.0f + __expf(-fabsf(z)));
}
__device__ __forceinline__ unsigned pack2bf(float a, float b) {
    __hip_bfloat162 t = __float22bfloat162_rn(make_float2(a, b));
    return *(unsigned*)&t;
}
__device__ __forceinline__ short f2bf_s(float x) {
    bf16 h = __float2bfloat16(x); return *(short*)&h;
}
__device__ __forceinline__ v8s make_v8(float4 f0, float4 f1) {
    v8s r;
    r[0] = f2bf_s(f0.x); r[1] = f2bf_s(f0.y); r[2] = f2bf_s(f0.z); r[3] = f2bf_s(f0.w);
    r[4] = f2bf_s(f1.x); r[5] = f2bf_s(f1.y); r[6] = f2bf_s(f1.z); r[7] = f2bf_s(f1.w);
    return r;
}

// ---------------------------------------------------------------------------
// Weight prep:
//  [0,192):     Wvo[b] = Wo[b]@Wv[b] -> bf16 (4 rows/block); bvo = Wo@bv + bo
//  [192,960):   Wl  -> bf16, K-pad 168->192
//  [960,1728):  Wl1 -> bf16
//  [1728,2304): W20 -> bf16, rows padded 168->192 (zeros)
//  [2304,2336): Wfc2 -> bf16, rows 24->32 (zeros), K-pad 168->192
// ---------------------------------------------------------------------------
__global__ __launch_bounds__(256) void wprep(
    const float* __restrict__ Wl, const float* __restrict__ Wl1,
    const float* __restrict__ Wv, const float* __restrict__ bv,
    const float* __restrict__ Wo, const float* __restrict__ bo,
    const float* __restrict__ W20, const float* __restrict__ Wfc2,
    bf16* __restrict__ Wlb, bf16* __restrict__ Wl1b, bf16* __restrict__ Wvob,
    bf16* __restrict__ W20b, bf16* __restrict__ Wfc2b, float* __restrict__ bvo)
{
    const int blk = blockIdx.x, j = threadIdx.x;
    if (blk < 192) {
        const int b = blk / 64, n0 = (blk % 64) * 4;
        const float* wo0 = Wo + (size_t)(b * 256 + n0 + 0) * 256;
        const float* wo1 = Wo + (size_t)(b * 256 + n0 + 1) * 256;
        const float* wo2 = Wo + (size_t)(b * 256 + n0 + 2) * 256;
        const float* wo3 = Wo + (size_t)(b * 256 + n0 + 3) * 256;
        const float* Wv_b = Wv + (size_t)b * 65536;
        float a0 = 0.f, a1 = 0.f, a2 = 0.f, a3 = 0.f;
        #pragma unroll 4
        for (int t = 0; t < 256; ++t) {
            float v = Wv_b[(size_t)t * 256 + j];
            a0 = fmaf(wo0[t], v, a0); a1 = fmaf(wo1[t], v, a1);
            a2 = fmaf(wo2[t], v, a2); a3 = fmaf(wo3[t], v, a3);
        }
        Wvob[(size_t)(b * 256 + n0 + 0) * 256 + j] = __float2bfloat16(a0);
        Wvob[(size_t)(b * 256 + n0 + 1) * 256 + j] = __float2bfloat16(a1);
        Wvob[(size_t)(b * 256 + n0 + 2) * 256 + j] = __float2bfloat16(a2);
        Wvob[(size_t)(b * 256 + n0 + 3) * 256 + j] = __float2bfloat16(a3);

        __shared__ float4 red[256];
        const float bvv = bv[b * 256 + j];
        red[j] = make_float4(wo0[j] * bvv, wo1[j] * bvv, wo2[j] * bvv, wo3[j] * bvv);
        __syncthreads();
        for (int s = 128; s > 0; s >>= 1) {
            if (j < s) {
                float4 x0 = red[j], x1 = red[j + s];
                red[j] = make_float4(x0.x + x1.x, x0.y + x1.y, x0.z + x1.z, x0.w + x1.w);
            }
            __syncthreads();
        }
        if (j == 0) {
            float4 r0 = red[0];
            bvo[b * 256 + n0 + 0] = r0.x + bo[b * 256 + n0 + 0];
            bvo[b * 256 + n0 + 1] = r0.y + bo[b * 256 + n0 + 1];
            bvo[b * 256 + n0 + 2] = r0.z + bo[b * 256 + n0 + 2];
            bvo[b * 256 + n0 + 3] = r0.w + bo[b * 256 + n0 + 3];
        }
    } else if (blk < 960) {
        const int idx = blk - 192, b = idx >> 8, r = idx & 255;
        if (j < T_PAD)
            Wlb[(size_t)(b * 256 + r) * T_PAD + j] =
                __float2bfloat16(j < T_DIM ? Wl[(size_t)(b * 256 + r) * T_DIM + j] : 0.f);
    } else if (blk < 1728) {
        const int idx = blk - 960, b = idx >> 8, r = idx & 255;
        Wl1b[(size_t)(b * 256 + r) * 256 + j] =
            __float2bfloat16(Wl1[(size_t)(b * 256 + r) * 256 + j]);
    } else if (blk < 2304) {
        const int idx = blk - 1728, b = idx / T_PAD, r = idx % T_PAD;
        W20b[(size_t)(b * T_PAD + r) * 256 + j] =
            __float2bfloat16(r < T_DIM ? W20[(size_t)(b * T_DIM + r) * 256 + j] : 0.f);
    } else {
        const int r = blk - 2304;   // 0..31
        if (j < T_PAD)
            Wfc2b[r * T_PAD + j] =
                __float2bfloat16((r < HOR && j < T_DIM) ? Wfc2[r * T_DIM + j] : 0.f);
    }
}

// ---------------------------------------------------------------------------
// Persistent fused network. 238 blocks x 512 threads (8 waves), 80 rows/block.
// ALL activations + f32 residual live in LDS; x read once, out written once.
// Swapped MFMA: A = weight rows (global, L2-hot), B = activation rows.
// h LDS layout  (bf16, stride 512 B): byte row*512 + ((2*col) ^ ((row&7)<<4))
// hX LDS layout (f32,  stride 768 B): byte row*768 + ((4*col) ^ ((row&7)<<4))
// NOTE (R8 bug fix): XOR must be applied to EACH quad's unswizzled offset;
// (u ^ swz) + 16 != (u + 16) ^ swz when swz bit4 is set.
// D frag: lane (r16,kq) holds out[row=16j+r16][cols c0+4kq+e], e=0..3.
// ---------------------------------------------------------------------------
__global__ __launch_bounds__(512, 2) void fused_net(
    const bf16* __restrict__ Wlb, const bf16* __restrict__ Wl1b,
    const bf16* __restrict__ Wvob, const bf16* __restrict__ W20b,
    const bf16* __restrict__ Wfc2b, const float* __restrict__ bvo,
    const float* __restrict__ x, float* __restrict__ out)
{
    __shared__ __align__(16) bf16  hA[RPB * 256];   // 40 KB
    __shared__ __align__(16) bf16  hB[RPB * 256];   // 40 KB
    __shared__ __align__(16) float hX[RPB * 192];   // 60 KB f32 residual

    const int tid  = threadIdx.x;
    const int lane = tid & 63, w = tid >> 6;        // 8 waves
    const int r16  = lane & 15, kq = lane >> 4;
    const int swz  = (r16 & 7) << 4;
    const int bm   = blockIdx.x * RPB;

    // ---- stage x rows [bm, bm+80) into hX (f32, swizzled, zero-padded) ----
    for (int u = tid; u < RPB * 48; u += 512) {
        const int r = u / 48, q = u - r * 48;       // col quad q: cols 4q..4q+3
        const int gr = bm + r;
        float4 v = make_float4(0.f, 0.f, 0.f, 0.f);
        if (gr < N_TS && q < 42)
            v = *(const float4*)&x[(size_t)gr * T_DIM + 4 * q];
        *(float4*)((char*)hX + r * 768 + ((16 * q) ^ ((r & 7) << 4))) = v;
    }
    __syncthreads();

    for (int b = 0; b < NBLK; ++b) {
        // ---- GEMM1: hA = softplus(hX @ Wl^T); K=192; wave w: h-cols [32w,32w+32) ----
        {
            const bf16* W = Wlb + (size_t)b * 256 * T_PAD;
            v8s wreg[2][6];
            #pragma unroll
            for (int i = 0; i < 2; ++i)
                #pragma unroll
                for (int ks = 0; ks < 6; ++ks)
                    wreg[i][ks] = *(const v8s*)&W[(size_t)(32 * w + 16 * i + r16) * T_PAD + ks * 32 + 8 * kq];
            v4f acc[2][5] = {};
            #pragma unroll
            for (int ks = 0; ks < 6; ++ks)
                #pragma unroll
                for (int j = 0; j < 5; ++j) {
                    const char* base = (const char*)hX + (16 * j + r16) * 768;
                    const int   u0   = 128 * ks + 32 * kq;           // unswizzled byte
                    float4 f0 = *(const float4*)(base + (u0 ^ swz));
                    float4 f1 = *(const float4*)(base + ((u0 + 16) ^ swz));
                    v8s bfr = make_v8(f0, f1);
                    acc[0][j] = __builtin_amdgcn_mfma_f32_16x16x32_bf16(wreg[0][ks], bfr, acc[0][j], 0, 0, 0);
                    acc[1][j] = __builtin_amdgcn_mfma_f32_16x16x32_bf16(wreg[1][ks], bfr, acc[1][j], 0, 0, 0);
                }
            #pragma unroll
            for (int i = 0; i < 2; ++i)
                #pragma unroll
                for (int j = 0; j < 5; ++j) {
                    float v0 = softplus_f(acc[i][j][0]), v1 = softplus_f(acc[i][j][1]);
                    float v2 = softplus_f(acc[i][j][2]), v3 = softplus_f(acc[i][j][3]);
                    const int c0  = 32 * w + 16 * i + 4 * kq;
                    const int off = (16 * j + r16) * 512 + ((2 * c0) ^ swz);
                    *(uint2*)((char*)hA + off) = make_uint2(pack2bf(v0, v1), pack2bf(v2, v3));
                }
        }
        __syncthreads();

        // ---- GEMM2: hB = softplus(hA @ Wl1^T); K=256 ----
        {
            const bf16* W = Wl1b + (size_t)b * 65536;
            v8s wreg[2][8];
            #pragma unroll
            for (int i = 0; i < 2; ++i)
                #pragma unroll
                for (int ks = 0; ks < 8; ++ks)
                    wreg[i][ks] = *(const v8s*)&W[(size_t)(32 * w + 16 * i + r16) * 256 + ks * 32 + 8 * kq];
            v4f acc[2][5] = {};
            #pragma unroll
            for (int ks = 0; ks < 8; ++ks)
                #pragma unroll
                for (int j = 0; j < 5; ++j) {
                    v8s bfr = *(const v8s*)((const char*)hA + (16 * j + r16) * 512 +
                                            ((64 * ks + 16 * kq) ^ swz));
                    acc[0][j] = __builtin_amdgcn_mfma_f32_16x16x32_bf16(wreg[0][ks], bfr, acc[0][j], 0, 0, 0);
                    acc[1][j] = __builtin_amdgcn_mfma_f32_16x16x32_bf16(wreg[1][ks], bfr, acc[1][j], 0, 0, 0);
                }
            #pragma unroll
            for (int i = 0; i < 2; ++i)
                #pragma unroll
                for (int j = 0; j < 5; ++j) {
                    float v0 = softplus_f(acc[i][j][0]), v1 = softplus_f(acc[i][j][1]);
                    float v2 = softplus_f(acc[i][j][2]), v3 = softplus_f(acc[i][j][3]);
                    const int c0  = 32 * w + 16 * i + 4 * kq;
                    const int off = (16 * j + r16) * 512 + ((2 * c0) ^ swz);
                    *(uint2*)((char*)hB + off) = make_uint2(pack2bf(v0, v1), pack2bf(v2, v3));
                }
        }
        __syncthreads();

        // ---- GEMM3: hA = hB @ Wvo^T + bvo; K=256 ----
        {
            const bf16* W = Wvob + (size_t)b * 65536;
            v8s wreg[2][8];
            #pragma unroll
            for (int i = 0; i < 2; ++i)
                #pragma unroll
                for (int ks = 0; ks < 8; ++ks)
                    wreg[i][ks] = *(const v8s*)&W[(size_t)(32 * w + 16 * i + r16) * 256 + ks * 32 + 8 * kq];
            v4f acc[2][5] = {};
            #pragma unroll
            for (int ks = 0; ks < 8; ++ks)
                #pragma unroll
                for (int j = 0; j < 5; ++j) {
                    v8s bfr = *(const v8s*)((const char*)hB + (16 * j + r16) * 512 +
                                            ((64 * ks + 16 * kq) ^ swz));
                    acc[0][j] = __builtin_amdgcn_mfma_f32_16x16x32_bf16(wreg[0][ks], bfr, acc[0][j], 0, 0, 0);
                    acc[1][j] = __builtin_amdgcn_mfma_f32_16x16x32_bf16(wreg[1][ks], bfr, acc[1][j], 0, 0, 0);
                }
            #pragma unroll
            for (int i = 0; i < 2; ++i) {
                const int c0b = 32 * w + 16 * i + 4 * kq;
                float4 bb = *(const float4*)&bvo[b * 256 + c0b];
                #pragma unroll
                for (int j = 0; j < 5; ++j) {
                    float v0 = acc[i][j][0] + bb.x, v1 = acc[i][j][1] + bb.y;
                    float v2 = acc[i][j][2] + bb.z, v3 = acc[i][j][3] + bb.w;
                    const int off = (16 * j + r16) * 512 + ((2 * c0b) ^ swz);
                    *(uint2*)((char*)hA + off) = make_uint2(pack2bf(v0, v1), pack2bf(v2, v3));
                }
            }
        }
        __syncthreads();

        // ---- GEMM4: hX += hA @ W20^T (f32 RMW in LDS); 12 col-tiles over 8 waves ----
        {
            const bf16* W = W20b + (size_t)b * T_PAD * 256;
            const int ti0 = (w < 4) ? 2 * w : 8 + (w - 4);
            const int nti = (w < 4) ? 2 : 1;
            v8s wreg[2][8];
            #pragma unroll
            for (int i = 0; i < 2; ++i)
                if (i < nti)
                    #pragma unroll
                    for (int ks = 0; ks < 8; ++ks)
                        wreg[i][ks] = *(const v8s*)&W[(size_t)(16 * (ti0 + i) + r16) * 256 + ks * 32 + 8 * kq];
            v4f acc[2][5] = {};
            #pragma unroll
            for (int ks = 0; ks < 8; ++ks)
                #pragma unroll
                for (int j = 0; j < 5; ++j) {
                    v8s bfr = *(const v8s*)((const char*)hA + (16 * j + r16) * 512 +
                                            ((64 * ks + 16 * kq) ^ swz));
                    #pragma unroll
                    for (int i = 0; i < 2; ++i)
                        if (i < nti)
                            acc[i][j] = __builtin_amdgcn_mfma_f32_16x16x32_bf16(wreg[i][ks], bfr, acc[i][j], 0, 0, 0);
                }
            #pragma unroll
            for (int i = 0; i < 2; ++i)
                if (i < nti)
                    #pragma unroll
                    for (int j = 0; j < 5; ++j) {
                        const int c0 = 16 * (ti0 + i) + 4 * kq;
                        char* p = (char*)hX + (16 * j + r16) * 768 + ((4 * c0) ^ swz);
                        float4 v = *(float4*)p;
                        v.x += acc[i][j][0]; v.y += acc[i][j][1];
                        v.z += acc[i][j][2]; v.w += acc[i][j][3];
                        *(float4*)p = v;
                    }
        }
        __syncthreads();
    }

    // ---- fc2: out = hX @ Wfc2^T; 10 units (t,j): t=out-col-tile, j=row-tile ----
    for (int u = w; u < 10; u += 8) {
        const int t = u & 1, j = u >> 1;
        v4f acc = {};
        #pragma unroll
        for (int ks = 0; ks < 6; ++ks) {
            const char* base = (const char*)hX + (16 * j + r16) * 768;
            const int   u0   = 128 * ks + 32 * kq;
            float4 f0 = *(const float4*)(base + (u0 ^ swz));
            float4 f1 = *(const float4*)(base + ((u0 + 16) ^ swz));
            v8s xv = make_v8(f0, f1);
            v8s a  = *(const v8s*)&Wfc2b[(size_t)(16 * t + r16) * T_PAD + ks * 32 + 8 * kq];
            acc = __builtin_amdgcn_mfma_f32_16x16x32_bf16(a, xv, acc, 0, 0, 0);
        }
        const int grow = bm + 16 * j + r16;
        const int col  = 16 * t + 4 * kq;
        if (grow < N_TS && col < HOR)
            *(float4*)&out[(size_t)grow * HOR + col] =
                make_float4(acc[0], acc[1], acc[2], acc[3]);
    }
}

// ---------------------------------------------------------------------------
extern "C" void kernel_launch(void* const* d_in, const int* in_sizes, int n_in,
                              void* d_out, int out_size, void* d_ws, size_t ws_size,
                              hipStream_t stream) {
    const float* x    = (const float*)d_in[0];
    const float* Wl   = (const float*)d_in[1];
    const float* Wl1  = (const float*)d_in[2];
    const float* Wv   = (const float*)d_in[7];
    const float* bv   = (const float*)d_in[8];
    const float* Wo   = (const float*)d_in[9];
    const float* bo   = (const float*)d_in[10];
    const float* W20  = (const float*)d_in[11];
    const float* Wfc2 = (const float*)d_in[12];
    float* out = (float*)d_out;

    char* p = (char*)d_ws;
    auto carve = [&](size_t bytes) { char* q = p; p += (bytes + 255) & ~(size_t)255; return q; };
    bf16*  Wlb   = (bf16*)carve((size_t)NBLK * 256 * T_PAD * 2);
    bf16*  Wl1b  = (bf16*)carve((size_t)NBLK * 256 * 256 * 2);
    bf16*  Wvob  = (bf16*)carve((size_t)NBLK * 256 * 256 * 2);
    bf16*  W20b  = (bf16*)carve((size_t)NBLK * T_PAD * 256 * 2);
    bf16*  Wfc2b = (bf16*)carve((size_t)32 * T_PAD * 2);
    float* bvo   = (float*)carve((size_t)NBLK * 256 * 4);

    wprep<<<dim3(2336), dim3(256), 0, stream>>>(
        Wl, Wl1, Wv, bv, Wo, bo, W20, Wfc2, Wlb, Wl1b, Wvob, W20b, Wfc2b, bvo);
    fused_net<<<dim3(NBLKS), dim3(512), 0, stream>>>(
        Wlb, Wl1b, Wvob, W20b, Wfc2b, bvo, x, out);
}

// Round 10
// 167.819 us; speedup vs baseline: 2.0553x; 1.0356x over previous
//
#include <hip/hip_runtime.h>
#include <hip/hip_bf16.h>
#include <math.h>

#define N_TS   19000
#define RPB    80         // rows per block (5 j-tiles of 16)
#define NBLKS  238        // 238*80 = 19040 >= 19000
#define T_DIM  168
#define T_PAD  192        // 6 * 32
#define U_DIM  256
#define NBLK   3
#define HOR    24

using bf16 = __hip_bfloat16;
typedef short v8s __attribute__((ext_vector_type(8)));   // 8 bf16 (MFMA A/B frag)
typedef float v4f __attribute__((ext_vector_type(4)));   // MFMA C/D frag

#define MFMA(a, b, c) __builtin_amdgcn_mfma_f32_16x16x32_bf16((a), (b), (c), 0, 0, 0)

// Raw barrier: drain LDS ops (cross-wave ordering) but leave global loads
// in flight -- __syncthreads() would emit s_waitcnt vmcnt(0) and kill the
// cross-phase weight prefetch.
#define BAR() do { asm volatile("s_waitcnt lgkmcnt(0)" ::: "memory"); \
                   __builtin_amdgcn_s_barrier(); } while (0)

__device__ __forceinline__ float softplus_f(float z) {
    return fmaxf(z, 0.0f) + __logf(1.0f + __expf(-fabsf(z)));
}
__device__ __forceinline__ unsigned pack2bf(float a, float b) {
    __hip_bfloat162 t = __float22bfloat162_rn(make_float2(a, b));
    return *(unsigned*)&t;
}
__device__ __forceinline__ short f2bf_s(float x) {
    bf16 h = __float2bfloat16(x); return *(short*)&h;
}
__device__ __forceinline__ v8s make_v8(float4 f0, float4 f1) {
    v8s r;
    r[0] = f2bf_s(f0.x); r[1] = f2bf_s(f0.y); r[2] = f2bf_s(f0.z); r[3] = f2bf_s(f0.w);
    r[4] = f2bf_s(f1.x); r[5] = f2bf_s(f1.y); r[6] = f2bf_s(f1.z); r[7] = f2bf_s(f1.w);
    return r;
}

// ---------------------------------------------------------------------------
// Weight prep (unchanged from R9):
//  [0,192):     Wvo[b] = Wo[b]@Wv[b] -> bf16 (4 rows/block); bvo = Wo@bv + bo
//  [192,960):   Wl  -> bf16, K-pad 168->192
//  [960,1728):  Wl1 -> bf16
//  [1728,2304): W20 -> bf16, rows padded 168->192 (zeros)
//  [2304,2336): Wfc2 -> bf16, rows 24->32 (zeros), K-pad 168->192
// ---------------------------------------------------------------------------
__global__ __launch_bounds__(256) void wprep(
    const float* __restrict__ Wl, const float* __restrict__ Wl1,
    const float* __restrict__ Wv, const float* __restrict__ bv,
    const float* __restrict__ Wo, const float* __restrict__ bo,
    const float* __restrict__ W20, const float* __restrict__ Wfc2,
    bf16* __restrict__ Wlb, bf16* __restrict__ Wl1b, bf16* __restrict__ Wvob,
    bf16* __restrict__ W20b, bf16* __restrict__ Wfc2b, float* __restrict__ bvo)
{
    const int blk = blockIdx.x, j = threadIdx.x;
    if (blk < 192) {
        const int b = blk / 64, n0 = (blk % 64) * 4;
        const float* wo0 = Wo + (size_t)(b * 256 + n0 + 0) * 256;
        const float* wo1 = Wo + (size_t)(b * 256 + n0 + 1) * 256;
        const float* wo2 = Wo + (size_t)(b * 256 + n0 + 2) * 256;
        const float* wo3 = Wo + (size_t)(b * 256 + n0 + 3) * 256;
        const float* Wv_b = Wv + (size_t)b * 65536;
        float a0 = 0.f, a1 = 0.f, a2 = 0.f, a3 = 0.f;
        #pragma unroll 4
        for (int t = 0; t < 256; ++t) {
            float v = Wv_b[(size_t)t * 256 + j];
            a0 = fmaf(wo0[t], v, a0); a1 = fmaf(wo1[t], v, a1);
            a2 = fmaf(wo2[t], v, a2); a3 = fmaf(wo3[t], v, a3);
        }
        Wvob[(size_t)(b * 256 + n0 + 0) * 256 + j] = __float2bfloat16(a0);
        Wvob[(size_t)(b * 256 + n0 + 1) * 256 + j] = __float2bfloat16(a1);
        Wvob[(size_t)(b * 256 + n0 + 2) * 256 + j] = __float2bfloat16(a2);
        Wvob[(size_t)(b * 256 + n0 + 3) * 256 + j] = __float2bfloat16(a3);

        __shared__ float4 red[256];
        const float bvv = bv[b * 256 + j];
        red[j] = make_float4(wo0[j] * bvv, wo1[j] * bvv, wo2[j] * bvv, wo3[j] * bvv);
        __syncthreads();
        for (int s = 128; s > 0; s >>= 1) {
            if (j < s) {
                float4 x0 = red[j], x1 = red[j + s];
                red[j] = make_float4(x0.x + x1.x, x0.y + x1.y, x0.z + x1.z, x0.w + x1.w);
            }
            __syncthreads();
        }
        if (j == 0) {
            float4 r0 = red[0];
            bvo[b * 256 + n0 + 0] = r0.x + bo[b * 256 + n0 + 0];
            bvo[b * 256 + n0 + 1] = r0.y + bo[b * 256 + n0 + 1];
            bvo[b * 256 + n0 + 2] = r0.z + bo[b * 256 + n0 + 2];
            bvo[b * 256 + n0 + 3] = r0.w + bo[b * 256 + n0 + 3];
        }
    } else if (blk < 960) {
        const int idx = blk - 192, b = idx >> 8, r = idx & 255;
        if (j < T_PAD)
            Wlb[(size_t)(b * 256 + r) * T_PAD + j] =
                __float2bfloat16(j < T_DIM ? Wl[(size_t)(b * 256 + r) * T_DIM + j] : 0.f);
    } else if (blk < 1728) {
        const int idx = blk - 960, b = idx >> 8, r = idx & 255;
        Wl1b[(size_t)(b * 256 + r) * 256 + j] =
            __float2bfloat16(Wl1[(size_t)(b * 256 + r) * 256 + j]);
    } else if (blk < 2304) {
        const int idx = blk - 1728, b = idx / T_PAD, r = idx % T_PAD;
        W20b[(size_t)(b * T_PAD + r) * 256 + j] =
            __float2bfloat16(r < T_DIM ? W20[(size_t)(b * T_DIM + r) * 256 + j] : 0.f);
    } else {
        const int r = blk - 2304;   // 0..31
        if (j < T_PAD)
            Wfc2b[r * T_PAD + j] =
                __float2bfloat16((r < HOR && j < T_DIM) ? Wfc2[r * T_DIM + j] : 0.f);
    }
}

// ---------------------------------------------------------------------------
// Weight loader into register double-buffer. Layout dst[i*NKS + ks].
// ---------------------------------------------------------------------------
template<int NKS, int NI>
__device__ __forceinline__ void loadW(v8s (&dst)[16], const bf16* __restrict__ W,
                                      int ld, int rowA, int rowB, int kq)
{
    #pragma unroll
    for (int i = 0; i < NI; ++i) {
        const int r = (i == 0) ? rowA : rowB;
        #pragma unroll
        for (int ks = 0; ks < NKS; ++ks)
            dst[i * NKS + ks] = *(const v8s*)&W[(size_t)r * ld + ks * 32 + 8 * kq];
    }
}

// ---------------------------------------------------------------------------
// h-to-h GEMM phase: dst = act(src @ W^T (+bias)); wave w owns cols [32w,32w+32).
// src/dst are swizzled bf16 LDS tiles (stride 512 B, byte (2c)^((row&7)<<4)).
// ---------------------------------------------------------------------------
template<int NKS, bool SP, bool BIAS>
__device__ __forceinline__ void computeH(const v8s (&wreg)[16],
    const char* src, char* dst, const float* __restrict__ bias,
    int w, int r16, int kq, int swz)
{
    v4f acc[2][5] = {};
    #pragma unroll
    for (int ks = 0; ks < NKS; ++ks)
        #pragma unroll
        for (int j = 0; j < 5; ++j) {
            v8s bfr = *(const v8s*)(src + (16 * j + r16) * 512 + ((64 * ks + 16 * kq) ^ swz));
            acc[0][j] = MFMA(wreg[0 * NKS + ks], bfr, acc[0][j]);
            acc[1][j] = MFMA(wreg[1 * NKS + ks], bfr, acc[1][j]);
        }
    #pragma unroll
    for (int i = 0; i < 2; ++i) {
        const int c0 = 32 * w + 16 * i + 4 * kq;
        float4 bb = make_float4(0.f, 0.f, 0.f, 0.f);
        if (BIAS) bb = *(const float4*)&bias[c0];
        #pragma unroll
        for (int j = 0; j < 5; ++j) {
            float v0 = acc[i][j][0], v1 = acc[i][j][1], v2 = acc[i][j][2], v3 = acc[i][j][3];
            if (BIAS) { v0 += bb.x; v1 += bb.y; v2 += bb.z; v3 += bb.w; }
            if (SP) { v0 = softplus_f(v0); v1 = softplus_f(v1);
                      v2 = softplus_f(v2); v3 = softplus_f(v3); }
            *(uint2*)(dst + (16 * j + r16) * 512 + ((2 * c0) ^ swz)) =
                make_uint2(pack2bf(v0, v1), pack2bf(v2, v3));
        }
    }
}

// ---------------------------------------------------------------------------
// Persistent fused network. 238 blocks x 512 threads (8 waves), 80 rows/block.
// All activations + f32 residual in LDS. Raw barriers (lgkmcnt-only) so the
// double-buffered weight prefetch (wE/wO) stays in flight across phases.
// G4 writes BOTH f32 residual (hX) and its bf16 image (into hB = hXb) so G1
// reads bf16 directly (no f32->bf16 cvt in the hot loop).
// ---------------------------------------------------------------------------
__global__ __launch_bounds__(512, 2) void fused_net(
    const bf16* __restrict__ Wlb, const bf16* __restrict__ Wl1b,
    const bf16* __restrict__ Wvob, const bf16* __restrict__ W20b,
    const bf16* __restrict__ Wfc2b, const float* __restrict__ bvo,
    const float* __restrict__ x, float* __restrict__ out)
{
    __shared__ __align__(16) bf16  hA[RPB * 256];   // 40 KB
    __shared__ __align__(16) bf16  hB[RPB * 256];   // 40 KB (doubles as hXb)
    __shared__ __align__(16) float hX[RPB * 192];   // 60 KB f32 residual

    const int tid  = threadIdx.x;
    const int lane = tid & 63, w = tid >> 6;        // 8 waves
    const int r16  = lane & 15, kq = lane >> 4;
    const int swz  = (r16 & 7) << 4;
    const int bm   = blockIdx.x * RPB;

    v8s wE[16], wO[16];

    // prefetch G1(b=0) weights, then stage x into hX (f32) + hXb (bf16, in hB)
    loadW<6, 2>(wE, Wlb, T_PAD, 32 * w + r16, 32 * w + 16 + r16, kq);

    for (int u = tid; u < RPB * 48; u += 512) {
        const int r = u / 48, q = u - r * 48;       // col quad q: cols 4q..4q+3
        const int gr = bm + r;
        float4 v = make_float4(0.f, 0.f, 0.f, 0.f);
        if (gr < N_TS && q < 42)
            v = *(const float4*)&x[(size_t)gr * T_DIM + 4 * q];
        const int sr = (r & 7) << 4;
        *(float4*)((char*)hX + r * 768 + ((16 * q) ^ sr)) = v;
        *(uint2*)((char*)hB + r * 512 + ((8 * q) ^ sr)) =
            make_uint2(pack2bf(v.x, v.y), pack2bf(v.z, v.w));
    }
    BAR();

    for (int b = 0; b < NBLK; ++b) {
        // ---- G1: hA = softplus(hXb @ Wl^T) [uses wE]; prefetch G2 -> wO ----
        loadW<8, 2>(wO, Wl1b + (size_t)b * 65536, 256,
                    32 * w + r16, 32 * w + 16 + r16, kq);
        computeH<6, true, false>(wE, (const char*)hB, (char*)hA, nullptr, w, r16, kq, swz);
        BAR();

        // ---- G2: hB = softplus(hA @ Wl1^T) [uses wO]; prefetch G3 -> wE ----
        loadW<8, 2>(wE, Wvob + (size_t)b * 65536, 256,
                    32 * w + r16, 32 * w + 16 + r16, kq);
        computeH<8, true, false>(wO, (const char*)hA, (char*)hB, nullptr, w, r16, kq, swz);
        BAR();

        // ---- G3: hA = hB @ Wvo^T + bvo [uses wE]; prefetch G4 -> wO ----
        {
            const bf16* W4 = W20b + (size_t)b * T_PAD * 256;
            if (w < 4) loadW<8, 2>(wO, W4, 256, 16 * (2 * w) + r16, 16 * (2 * w + 1) + r16, kq);
            else       loadW<8, 1>(wO, W4, 256, 16 * (8 + w - 4) + r16, 0, kq);
        }
        computeH<8, false, true>(wE, (const char*)hB, (char*)hA, bvo + b * 256, w, r16, kq, swz);
        BAR();

        // ---- G4: hX += hA @ W20^T (f32 RMW) + bf16 image -> hB (hXb) [uses wO];
        //      prefetch G1(b+1) or fc2 weights -> wE ----
        if (b < NBLK - 1) {
            loadW<6, 2>(wE, Wlb + (size_t)(b + 1) * 256 * T_PAD, T_PAD,
                        32 * w + r16, 32 * w + 16 + r16, kq);
        } else {
            #pragma unroll
            for (int ks = 0; ks < 6; ++ks)
                wE[ks] = *(const v8s*)&Wfc2b[(size_t)(16 * (w & 1) + r16) * T_PAD + ks * 32 + 8 * kq];
        }
        {
            const int ti0 = (w < 4) ? 2 * w : 8 + (w - 4);
            v4f acc[2][5] = {};
            #pragma unroll
            for (int ks = 0; ks < 8; ++ks)
                #pragma unroll
                for (int j = 0; j < 5; ++j) {
                    v8s bfr = *(const v8s*)((const char*)hA + (16 * j + r16) * 512 +
                                            ((64 * ks + 16 * kq) ^ swz));
                    acc[0][j] = MFMA(wO[ks], bfr, acc[0][j]);
                    if (w < 4) acc[1][j] = MFMA(wO[8 + ks], bfr, acc[1][j]);
                }
            #pragma unroll
            for (int i = 0; i < 2; ++i) {
                if (i == 1 && w >= 4) continue;
                const int c0 = 16 * (ti0 + i) + 4 * kq;
                #pragma unroll
                for (int j = 0; j < 5; ++j) {
                    const int row = 16 * j + r16;
                    char* pX = (char*)hX + row * 768 + ((4 * c0) ^ swz);
                    float4 v = *(float4*)pX;
                    v.x += acc[i][j][0]; v.y += acc[i][j][1];
                    v.z += acc[i][j][2]; v.w += acc[i][j][3];
                    *(float4*)pX = v;
                    *(uint2*)((char*)hB + row * 512 + ((2 * c0) ^ swz)) =
                        make_uint2(pack2bf(v.x, v.y), pack2bf(v.z, v.w));
                }
            }
        }
        BAR();
    }

    // ---- fc2: out = hX @ Wfc2^T [uses wE[0..5]]; units u: t=u&1(==w&1), j=u>>1 ----
    for (int u = w; u < 10; u += 8) {
        const int j = u >> 1;
        v4f acc = {};
        #pragma unroll
        for (int ks = 0; ks < 6; ++ks) {
            const char* base = (const char*)hX + (16 * j + r16) * 768;
            const int   u0   = 128 * ks + 32 * kq;
            float4 f0 = *(const float4*)(base + (u0 ^ swz));
            float4 f1 = *(const float4*)(base + ((u0 + 16) ^ swz));
            v8s xv = make_v8(f0, f1);
            acc = MFMA(wE[ks], xv, acc);
        }
        const int grow = bm + 16 * j + r16;
        const int col  = 16 * (u & 1) + 4 * kq;
        if (grow < N_TS && col < HOR)
            *(float4*)&out[(size_t)grow * HOR + col] =
                make_float4(acc[0], acc[1], acc[2], acc[3]);
    }
}

// ---------------------------------------------------------------------------
extern "C" void kernel_launch(void* const* d_in, const int* in_sizes, int n_in,
                              void* d_out, int out_size, void* d_ws, size_t ws_size,
                              hipStream_t stream) {
    const float* x    = (const float*)d_in[0];
    const float* Wl   = (const float*)d_in[1];
    const float* Wl1  = (const float*)d_in[2];
    const float* Wv   = (const float*)d_in[7];
    const float* bv   = (const float*)d_in[8];
    const float* Wo   = (const float*)d_in[9];
    const float* bo   = (const float*)d_in[10];
    const float* W20  = (const float*)d_in[11];
    const float* Wfc2 = (const float*)d_in[12];
    float* out = (float*)d_out;

    char* p = (char*)d_ws;
    auto carve = [&](size_t bytes) { char* q = p; p += (bytes + 255) & ~(size_t)255; return q; };
    bf16*  Wlb   = (bf16*)carve((size_t)NBLK * 256 * T_PAD * 2);
    bf16*  Wl1b  = (bf16*)carve((size_t)NBLK * 256 * 256 * 2);
    bf16*  Wvob  = (bf16*)carve((size_t)NBLK * 256 * 256 * 2);
    bf16*  W20b  = (bf16*)carve((size_t)NBLK * T_PAD * 256 * 2);
    bf16*  Wfc2b = (bf16*)carve((size_t)32 * T_PAD * 2);
    float* bvo   = (float*)carve((size_t)NBLK * 256 * 4);

    wprep<<<dim3(2336), dim3(256), 0, stream>>>(
        Wl, Wl1, Wv, bv, Wo, bo, W20, Wfc2, Wlb, Wl1b, Wvob, W20b, Wfc2b, bvo);
    fused_net<<<dim3(NBLKS), dim3(512), 0, stream>>>(
        Wlb, Wl1b, Wvob, W20b, Wfc2b, bvo, x, out);
}